// Round 5
// baseline (90.022 us; speedup 1.0000x reference)
//
#include <hip/hip_runtime.h>
#include <hip/hip_bf16.h>

// Problem: B=8, S=4096, D=1024. Inputs: x0[B,S,D] f32, x1[B,S,D] f32,
// skipping_probs[B,S] f32 (unused — keep mask already sampled), keep[B,S] i32.
// Output: two [B,S,D] f32 tensors, concatenated flat in d_out: kept rows
// compacted to the front (stable order), tail rows zeroed.
//
// Pure data movement: 268 MB writes + ~201 MB reads (~75% keep) = ~470 MB
// -> ~75 us floor at 6.3 TB/s copy ceiling. Fused single kernel: each block
// recomputes the per-batch compaction scan from keep[b,:] (16 KB, L2-hot)
// into LDS, then copies its 16 strided rows.
// R5: split the row loop into a branch-free gather-copy loop (unroll 4,
// deep VMEM pipelining) + a branch-free zero-fill loop, instead of a
// per-iteration uniform branch that fragments load issue.

#define BB 8
#define SS 4096
#define DD 1024
#define D4 (DD / 4)          // 256 float4 per row
#define BPB 256              // blocks per batch
#define RPB (SS / BPB)       // 16 rows per block, stride BPB

typedef float f4 __attribute__((ext_vector_type(4)));

__global__ __launch_bounds__(256) void fused_compact_kernel(
    const f4* __restrict__ x0,
    const f4* __restrict__ x1,
    const int* __restrict__ keep,
    f4* __restrict__ out0,
    f4* __restrict__ out1)
{
    __shared__ int lds_src[SS];      // dst r -> src s map for this batch (16 KB)
    __shared__ int wave_sums[4];

    const int t = threadIdx.x;               // 0..255
    const int b = blockIdx.x >> 8;           // batch (8)
    const int j = blockIdx.x & (BPB - 1);    // 0..255, stride offset in batch

    // ---- Phase 1: block-wide stable compaction scan of keep[b, :] ----
    // Thread t owns 16 consecutive timesteps [16t, 16t+16). 16 KB of int4
    // loads, L2-resident (only 8 distinct rows chip-wide).
    const int4* krow4 = (const int4*)(keep + b * SS);
    int kk[16];
    {
        const int4 a0 = krow4[4 * t + 0];
        const int4 a1 = krow4[4 * t + 1];
        const int4 a2 = krow4[4 * t + 2];
        const int4 a3 = krow4[4 * t + 3];
        kk[0]  = a0.x; kk[1]  = a0.y; kk[2]  = a0.z; kk[3]  = a0.w;
        kk[4]  = a1.x; kk[5]  = a1.y; kk[6]  = a1.z; kk[7]  = a1.w;
        kk[8]  = a2.x; kk[9]  = a2.y; kk[10] = a2.z; kk[11] = a2.w;
        kk[12] = a3.x; kk[13] = a3.y; kk[14] = a3.z; kk[15] = a3.w;
    }
    int local = 0;
    #pragma unroll
    for (int q = 0; q < 16; ++q) local += kk[q];

    const int lane = t & 63;
    const int wid  = t >> 6;                 // 0..3

    int incl = local;                        // wave-inclusive scan (64 lanes)
    #pragma unroll
    for (int off = 1; off < 64; off <<= 1) {
        int v = __shfl_up(incl, off, 64);
        if (lane >= off) incl += v;
    }
    if (lane == 63) wave_sums[wid] = incl;
    __syncthreads();

    int wave_off = 0, nk = 0;
    #pragma unroll
    for (int w = 0; w < 4; ++w) {
        const int v = wave_sums[w];
        if (w < wid) wave_off += v;
        nk += v;
    }

    int d = wave_off + incl - local;         // exclusive prefix for this thread
    const int base_s = t * 16;
    #pragma unroll
    for (int q = 0; q < 16; ++q) {
        if (kk[q]) lds_src[d++] = base_s + q;
    }
    __syncthreads();

    // ---- Phase 2: batch-local strided copy, branch-free loops ----
    // Block j handles rows j, j+256, ..., j+3840. icopy = how many of those
    // are kept (r < nk); the rest are zero-fill.
    const int icopy = (nk > j) ? ((nk - j + (BPB - 1)) >> 8) : 0;   // 0..16
    const int batch_base = b * SS * D4 + t;

    #pragma unroll 4
    for (int i = 0; i < icopy; ++i) {
        const int r = j + (i << 8);
        const int s = lds_src[r];            // uniform LDS broadcast
        const int dst_off = batch_base + r * D4;
        const int src_off = batch_base + s * D4;
        f4 v0 = __builtin_nontemporal_load(&x0[src_off]);
        f4 v1 = __builtin_nontemporal_load(&x1[src_off]);
        __builtin_nontemporal_store(v0, &out0[dst_off]);
        __builtin_nontemporal_store(v1, &out1[dst_off]);
    }

    const f4 z = {0.f, 0.f, 0.f, 0.f};
    #pragma unroll 4
    for (int i = icopy; i < RPB; ++i) {
        const int r = j + (i << 8);
        const int dst_off = batch_base + r * D4;
        __builtin_nontemporal_store(z, &out0[dst_off]);
        __builtin_nontemporal_store(z, &out1[dst_off]);
    }
}

extern "C" void kernel_launch(void* const* d_in, const int* in_sizes, int n_in,
                              void* d_out, int out_size, void* d_ws, size_t ws_size,
                              hipStream_t stream) {
    const f4* x0  = (const f4*)d_in[0];
    const f4* x1  = (const f4*)d_in[1];
    // d_in[2] = skipping_probs (unused: keep mask is pre-sampled)
    const int* keep = (const int*)d_in[3];

    float* out = (float*)d_out;
    f4* out0 = (f4*)out;
    f4* out1 = (f4*)(out + (size_t)BB * SS * DD);

    fused_compact_kernel<<<BB * BPB, 256, 0, stream>>>(x0, x1, keep, out0, out1);
}

// Round 6
// 75.658 us; speedup vs baseline: 1.1899x; 1.1899x over previous
//
#include <hip/hip_runtime.h>
#include <hip/hip_bf16.h>

// Problem: B=8, S=4096, D=1024. Inputs: x0[B,S,D] f32, x1[B,S,D] f32,
// skipping_probs[B,S] f32 (unused — keep mask already sampled), keep[B,S] i32.
// Output: two [B,S,D] f32 tensors, concatenated flat in d_out: kept rows
// compacted to the front (stable order), tail rows zeroed.
//
// Pure data movement: 268 MB writes + ~201 MB reads (~75% keep) = ~470 MB
// -> ~75 us floor at the 6.3 TB/s copy ceiling. Fused single kernel (R4
// structure, best = 88.6 us): each block recomputes the per-batch compaction
// scan from keep[b,:] (16 KB, L2-hot) into LDS, then copies its 16 strided
// rows (batch-local sliding-window mapping).
// R6 single change: REGULAR stores (not nt). Evidence: rocclr fill kernel
// writes 1 GiB at 7.0 TB/s with regular stores; nt-store no-allocate path
// may be slower. Loads stay nt (zero reuse, keep L2 for the keep-row bcast).

#define BB 8
#define SS 4096
#define DD 1024
#define D4 (DD / 4)          // 256 float4 per row
#define BPB 256              // blocks per batch
#define RPB (SS / BPB)       // 16 rows per block, stride BPB

typedef float f4 __attribute__((ext_vector_type(4)));

__global__ __launch_bounds__(256) void fused_compact_kernel(
    const f4* __restrict__ x0,
    const f4* __restrict__ x1,
    const int* __restrict__ keep,
    f4* __restrict__ out0,
    f4* __restrict__ out1)
{
    __shared__ int lds_src[SS];      // dst r -> src s map for this batch (16 KB)
    __shared__ int wave_sums[4];

    const int t = threadIdx.x;               // 0..255
    const int b = blockIdx.x >> 8;           // batch (8)
    const int j = blockIdx.x & (BPB - 1);    // 0..255, stride offset in batch

    // ---- Phase 1: block-wide stable compaction scan of keep[b, :] ----
    // Thread t owns 16 consecutive timesteps [16t, 16t+16). 16 KB of int4
    // loads, L2-resident (only 8 distinct rows chip-wide).
    const int4* krow4 = (const int4*)(keep + b * SS);
    int kk[16];
    {
        const int4 a0 = krow4[4 * t + 0];
        const int4 a1 = krow4[4 * t + 1];
        const int4 a2 = krow4[4 * t + 2];
        const int4 a3 = krow4[4 * t + 3];
        kk[0]  = a0.x; kk[1]  = a0.y; kk[2]  = a0.z; kk[3]  = a0.w;
        kk[4]  = a1.x; kk[5]  = a1.y; kk[6]  = a1.z; kk[7]  = a1.w;
        kk[8]  = a2.x; kk[9]  = a2.y; kk[10] = a2.z; kk[11] = a2.w;
        kk[12] = a3.x; kk[13] = a3.y; kk[14] = a3.z; kk[15] = a3.w;
    }
    int local = 0;
    #pragma unroll
    for (int q = 0; q < 16; ++q) local += kk[q];

    const int lane = t & 63;
    const int wid  = t >> 6;                 // 0..3

    int incl = local;                        // wave-inclusive scan (64 lanes)
    #pragma unroll
    for (int off = 1; off < 64; off <<= 1) {
        int v = __shfl_up(incl, off, 64);
        if (lane >= off) incl += v;
    }
    if (lane == 63) wave_sums[wid] = incl;
    __syncthreads();

    int wave_off = 0, nk = 0;
    #pragma unroll
    for (int w = 0; w < 4; ++w) {
        const int v = wave_sums[w];
        if (w < wid) wave_off += v;
        nk += v;
    }

    int d = wave_off + incl - local;         // exclusive prefix for this thread
    const int base_s = t * 16;
    #pragma unroll
    for (int q = 0; q < 16; ++q) {
        if (kk[q]) lds_src[d++] = base_s + q;
    }
    __syncthreads();

    // ---- Phase 2: batch-local grid-stride gather-copy ----
    // Block j handles rows j, j+256, ..., j+3840. At each iteration the 256
    // blocks of a batch collectively write one contiguous 1 MB sliding window.
    const int batch_base = b * SS * D4 + t;

    for (int i = 0; i < RPB; ++i) {
        const int r = j + (i << 8);          // output row within batch
        const int dst_off = batch_base + r * D4;
        if (r < nk) {
            const int s = lds_src[r];        // LDS broadcast (uniform addr)
            const int src_off = batch_base + s * D4;
            f4 v0 = __builtin_nontemporal_load(&x0[src_off]);
            f4 v1 = __builtin_nontemporal_load(&x1[src_off]);
            out0[dst_off] = v0;              // regular stores (R6 change)
            out1[dst_off] = v1;
        } else {
            const f4 z = {0.f, 0.f, 0.f, 0.f};
            out0[dst_off] = z;
            out1[dst_off] = z;
        }
    }
}

extern "C" void kernel_launch(void* const* d_in, const int* in_sizes, int n_in,
                              void* d_out, int out_size, void* d_ws, size_t ws_size,
                              hipStream_t stream) {
    const f4* x0  = (const f4*)d_in[0];
    const f4* x1  = (const f4*)d_in[1];
    // d_in[2] = skipping_probs (unused: keep mask is pre-sampled)
    const int* keep = (const int*)d_in[3];

    float* out = (float*)d_out;
    f4* out0 = (f4*)out;
    f4* out1 = (f4*)(out + (size_t)BB * SS * DD);

    fused_compact_kernel<<<BB * BPB, 256, 0, stream>>>(x0, x1, keep, out0, out1);
}